// Round 5
// baseline (566.702 us; speedup 1.0000x reference)
//
#include <hip/hip_runtime.h>
#include <hip/hip_bf16.h>

// DQTLinear: C[M][N] = x[M][K] @ W^T, W[n][k] = ternary[n][k]*scales[n*32+k/128]
// M=8192, N=4096, K=4096. ternary arrives as int32 (harness upcasts int inputs).
// R5 == R4 (R4 hit an acquisition timeout, never benched):
// fused prep (RNE bit-trick dequant) -> ws in [slice][row] conflict-free tiled
// layout; 256x256 GEMM with mfma_f32_32x32x16_bf16, R3's proven 4-phase counted-vmcnt.

#define M_DIM 8192
#define N_DIM 4096
#define K_DIM 4096
#define NGRP 32

#define BM 256
#define BN 256
#define NT 64               // K tiles of 64
#define SLOT_B 16384        // one kk-half: 4 slices x 256 rows x 16B
#define TILE_B 32768        // per matrix per K-tile
#define A_BYTES (32ull * NT * TILE_B)   // 64 MiB
#define B_BYTES (16ull * NT * TILE_B)   // 32 MiB
#define A_CHUNKS (32 * 64 * 2 * 1024)   // 4194304 16B-chunks
#define B_CHUNKS (16 * 64 * 2 * 1024)   // 2097152

typedef float f32x4 __attribute__((ext_vector_type(4)));
typedef float f32x16 __attribute__((ext_vector_type(16)));
typedef short bf16x8 __attribute__((ext_vector_type(8)));

// RNE fp32->bf16 (valid for non-NaN inputs), packs two into one u32.
__device__ __forceinline__ unsigned bfpack(unsigned lo, unsigned hi) {
  lo = (lo + 0x7FFFu + ((lo >> 16) & 1u)) >> 16;
  hi = (hi + 0x7FFFu + ((hi >> 16) & 1u)) & 0xFFFF0000u;
  return lo | hi;
}

// ---------------- fused prepass ----------------
// ws layouts (16B chunk c): slot = c>>10 ; w = c&1023 ; slice s = w>>8 ; row r = w&255
// A: slot = (bm*64+kt)*2+kk ; data = bf16(X[bm*256+r][kt*64+kk*32+s*8+e]), e=0..7
// B: slot = (bn*64+kt)*2+kk ; data = bf16(T*scale) same k mapping
__global__ void prep_ab(const float* __restrict__ X, const int* __restrict__ T,
                        const float* __restrict__ S, char* __restrict__ A,
                        char* __restrict__ B) {
  const int idx0 = blockIdx.x * blockDim.x + threadIdx.x;
  const int stride = gridDim.x * blockDim.x;
  for (int c = idx0; c < A_CHUNKS; c += stride) {
    int w = c & 1023, slot = c >> 10;
    int s = w >> 8, r = w & 255;
    int kk = slot & 1, kt = (slot >> 1) & 63, bm = slot >> 7;
    int gr = bm * 256 + r;
    int k0 = kt * 64 + kk * 32 + s * 8;
    const uint4* p = reinterpret_cast<const uint4*>(X + (size_t)gr * K_DIM + k0);
    uint4 u = p[0], v = p[1];
    uint4 o;
    o.x = bfpack(u.x, u.y);
    o.y = bfpack(u.z, u.w);
    o.z = bfpack(v.x, v.y);
    o.w = bfpack(v.z, v.w);
    *reinterpret_cast<uint4*>(A + (size_t)c * 16) = o;
  }
  for (int c = idx0; c < B_CHUNKS; c += stride) {
    int w = c & 1023, slot = c >> 10;
    int s = w >> 8, r = w & 255;
    int kk = slot & 1, kt = (slot >> 1) & 63, bn = slot >> 7;
    int gn = bn * 256 + r;
    int k0 = kt * 64 + kk * 32 + s * 8;
    unsigned su = __builtin_bit_cast(unsigned, S[(size_t)gn * NGRP + (kt >> 1)]);
    unsigned sb = (su + 0x7FFFu + ((su >> 16) & 1u)) >> 16;  // bf16(s), s>0
    const int4* p = reinterpret_cast<const int4*>(T + (size_t)gn * K_DIM + k0);
    int4 u = p[0], v = p[1];
    int t0[8] = {u.x, u.y, u.z, u.w, v.x, v.y, v.z, v.w};
    unsigned h[8];
#pragma unroll
    for (int e = 0; e < 8; ++e) {
      unsigned sgn = ((unsigned)(t0[e] >> 31)) & 0x8000u;
      h[e] = t0[e] ? (sb | sgn) : 0u;
    }
    uint4 o;
    o.x = h[0] | (h[1] << 16);
    o.y = h[2] | (h[3] << 16);
    o.z = h[4] | (h[5] << 16);
    o.w = h[6] | (h[7] << 16);
    *reinterpret_cast<uint4*>(B + (size_t)c * 16) = o;
  }
}

// ---------------- main GEMM: 256x256, 8 waves, 32x32x16 MFMA ----------------
__device__ __forceinline__ void gload16(const char* g, const char* l) {
  __builtin_amdgcn_global_load_lds(
      (const __attribute__((address_space(1))) void*)g,
      (__attribute__((address_space(3))) void*)l, 16, 0, 0);
}

__global__ __launch_bounds__(512, 2) void dqt_gemm32(
    const char* __restrict__ Aws, const char* __restrict__ Bws,
    float* __restrict__ C) {
  __shared__ __align__(16) char lds[131072];  // 2 bufs x {A_lo,A_hi,B_lo,B_hi} x 16KiB

  // T1: chunked XCD swizzle; per XCD 4 bm x 16 bn, bn fast
  int b = blockIdx.x;             // 512
  int xcd = b & 7, idx = b >> 3;
  int bm = xcd * 4 + (idx >> 4);  // 0..31
  int bn = idx & 15;              // 0..15

  const int tid = threadIdx.x;
  const int lane = tid & 63;
  const int wid = tid >> 6;       // 8 waves
  const int wr = wid >> 2;        // M half (128 rows)
  const int wc = wid & 3;         // N quarter (64 cols)
  const int l31 = lane & 31;
  const int lh = lane >> 5;

  const char* pA = Aws + ((size_t)bm << 21) + wid * 2048 + lane * 16;
  const char* pB = Bws + ((size_t)bn << 21) + wid * 2048 + lane * 16;
  const int sbase = wid * 2048;

#define STAGE(dstoff, src)                                \
  do {                                                    \
    gload16((src), lds + (dstoff) + sbase);               \
    gload16((src) + 1024, lds + (dstoff) + sbase + 1024); \
  } while (0)

  // frag byte offsets within a slot: slice(k)*4096 + row*16
  // A row = wr*128 + m*32 + l31 ; k-slice = k0/8 + lh ; frag = 8 consecutive k
  const int aoff = lh * 4096 + (wr * 128 + l31) * 16;          // + m*512 + (k0/8)*4096
  const int boff = 32768 + lh * 4096 + (wc * 64 + l31) * 16;   // + n*512 + (k0/8)*4096

  f32x16 acc[4][2] = {};

  // Prologue: tile0 full (8 loads) + tile1 kk0 pair (4 loads); retire tile0.
  STAGE(0, pA);                      // buf0 A_lo (t0 kk0)
  STAGE(16384, pA + 16384);          // buf0 A_hi (t0 kk1)
  STAGE(32768, pB);                  // buf0 B_lo
  STAGE(49152, pB + 16384);          // buf0 B_hi
  STAGE(65536, pA + 32768);          // buf1 A_lo (t1 kk0)
  STAGE(65536 + 32768, pB + 32768);  // buf1 B_lo
  asm volatile("s_waitcnt vmcnt(4)" ::: "memory");
  __builtin_amdgcn_s_barrier();

#pragma unroll 1
  for (int t = 0; t < NT; ++t) {
    const int cb = (t & 1) << 16;
    const int nb = (~t & 1) << 16;
    const char* sA1 = pA + (t + 1) * TILE_B;
    const char* sB1 = pB + (t + 1) * TILE_B;
    const char* sA2 = pA + (t + 2) * TILE_B;
    const char* sB2 = pB + (t + 2) * TILE_B;
    bf16x8 af[4], bq[2];

    // ---- ph1: kk0, k0=0 ; stage next-tile kk1 pair into nb ----
#pragma unroll
    for (int m = 0; m < 4; ++m)
      af[m] = *(const bf16x8*)(lds + cb + 0 + aoff + m * 512);
#pragma unroll
    for (int n = 0; n < 2; ++n)
      bq[n] = *(const bf16x8*)(lds + cb + 0 + boff + n * 512);
    if (t + 1 < NT) {
      STAGE(nb + 16384, sA1 + 16384);
      STAGE(nb + 49152, sB1 + 16384);
    }
    __builtin_amdgcn_s_barrier();
    __builtin_amdgcn_s_setprio(1);
#pragma unroll
    for (int m = 0; m < 4; ++m)
#pragma unroll
      for (int n = 0; n < 2; ++n)
        acc[m][n] = __builtin_amdgcn_mfma_f32_32x32x16_bf16(af[m], bq[n], acc[m][n], 0, 0, 0);
    __builtin_amdgcn_s_setprio(0);
    __builtin_amdgcn_s_barrier();

    // ---- ph2: kk0, k0=16 ----
#pragma unroll
    for (int m = 0; m < 4; ++m)
      af[m] = *(const bf16x8*)(lds + cb + 8192 + aoff + m * 512);
#pragma unroll
    for (int n = 0; n < 2; ++n)
      bq[n] = *(const bf16x8*)(lds + cb + 8192 + boff + n * 512);
    __builtin_amdgcn_s_barrier();
    __builtin_amdgcn_s_setprio(1);
#pragma unroll
    for (int m = 0; m < 4; ++m)
#pragma unroll
      for (int n = 0; n < 2; ++n)
        acc[m][n] = __builtin_amdgcn_mfma_f32_32x32x16_bf16(af[m], bq[n], acc[m][n], 0, 0, 0);
    __builtin_amdgcn_s_setprio(0);
    __builtin_amdgcn_s_barrier();

    // ---- ph3: kk1, k0=0 ; stage t+2 A_lo into cb (A_lo last read in ph2) ----
#pragma unroll
    for (int m = 0; m < 4; ++m)
      af[m] = *(const bf16x8*)(lds + cb + 16384 + aoff + m * 512);
#pragma unroll
    for (int n = 0; n < 2; ++n)
      bq[n] = *(const bf16x8*)(lds + cb + 16384 + boff + n * 512);
    if (t + 2 < NT) STAGE(cb + 0, sA2);
    __builtin_amdgcn_s_barrier();
    __builtin_amdgcn_s_setprio(1);
#pragma unroll
    for (int m = 0; m < 4; ++m)
#pragma unroll
      for (int n = 0; n < 2; ++n)
        acc[m][n] = __builtin_amdgcn_mfma_f32_32x32x16_bf16(af[m], bq[n], acc[m][n], 0, 0, 0);
    __builtin_amdgcn_s_setprio(0);
    __builtin_amdgcn_s_barrier();

    // ---- ph4: kk1, k0=16 ; stage t+2 B_lo ; counted vmcnt ----
#pragma unroll
    for (int m = 0; m < 4; ++m)
      af[m] = *(const bf16x8*)(lds + cb + 16384 + 8192 + aoff + m * 512);
#pragma unroll
    for (int n = 0; n < 2; ++n)
      bq[n] = *(const bf16x8*)(lds + cb + 16384 + 8192 + boff + n * 512);
    if (t + 2 < NT) STAGE(cb + 32768, sB2);
    __builtin_amdgcn_s_barrier();
    __builtin_amdgcn_s_setprio(1);
#pragma unroll
    for (int m = 0; m < 4; ++m)
#pragma unroll
      for (int n = 0; n < 2; ++n)
        acc[m][n] = __builtin_amdgcn_mfma_f32_32x32x16_bf16(af[m], bq[n], acc[m][n], 0, 0, 0);
    __builtin_amdgcn_s_setprio(0);
    // retires all of t+1's 8 loads, leaves t+2's kk0 pair (4) in flight
    if (t < NT - 3)
      asm volatile("s_waitcnt vmcnt(4)" ::: "memory");
    else
      asm volatile("s_waitcnt vmcnt(0)" ::: "memory");
    __builtin_amdgcn_s_barrier();
  }

  // Epilogue: 32x32 C/D map: col = lane&31, row = (q&3) + 8*(q>>2) + 4*(lane>>5)
  const int row0 = bm * BM + wr * 128 + 4 * lh;
  const int col0 = bn * BN + wc * 64 + l31;
#pragma unroll
  for (int m = 0; m < 4; ++m)
#pragma unroll
    for (int n = 0; n < 2; ++n) {
      float* cp = C + (size_t)(row0 + m * 32) * N_DIM + col0 + n * 32;
#pragma unroll
      for (int q = 0; q < 16; ++q)
        cp[(size_t)((q & 3) + 8 * (q >> 2)) * N_DIM] = acc[m][n][q];
    }
#undef STAGE
}

// ---------------- fallback (proven R2 kernel) if ws too small ----------------
struct StageRegs { float4 a0, a1, a2, a3; int4 b0, b1, b2, b3; float s; };

__device__ __forceinline__ void fb_issue(StageRegs& r, const float* __restrict__ X,
    const int* __restrict__ T, const float* __restrict__ S,
    int arow_g, int brow_g, int kt, int kq) {
  const int kbase = kt * 64;
  const float4* pa = reinterpret_cast<const float4*>(X + (size_t)arow_g * K_DIM + kbase + kq * 16);
  r.a0 = pa[0]; r.a1 = pa[1]; r.a2 = pa[2]; r.a3 = pa[3];
  const int4* pb = reinterpret_cast<const int4*>(T + (size_t)brow_g * K_DIM + kbase + kq * 16);
  r.b0 = pb[0]; r.b1 = pb[1]; r.b2 = pb[2]; r.b3 = pb[3];
  r.s = S[(size_t)brow_g * NGRP + (kt >> 1)];
}
__device__ __forceinline__ void fb_stage(const StageRegs& r, char* als, char* bls,
                                         int rrow, int kq) {
  const int xorv = (rrow & 7) << 4;
  const int base = rrow * 128 + kq * 32;
  const float* xf = (const float*)&r.a0;
  const int* wi = (const int*)&r.b0;
  bf16x8 av0, av1, wv0, wv1;
#pragma unroll
  for (int e = 0; e < 8; ++e) {
    av0[e] = __builtin_bit_cast(short, __float2bfloat16(xf[e]));
    av1[e] = __builtin_bit_cast(short, __float2bfloat16(xf[8 + e]));
    wv0[e] = __builtin_bit_cast(short, __float2bfloat16((float)wi[e] * r.s));
    wv1[e] = __builtin_bit_cast(short, __float2bfloat16((float)wi[8 + e] * r.s));
  }
  *(bf16x8*)(als + ((base) ^ xorv)) = av0;
  *(bf16x8*)(als + ((base + 16) ^ xorv)) = av1;
  *(bf16x8*)(bls + ((base) ^ xorv)) = wv0;
  *(bf16x8*)(bls + ((base + 16) ^ xorv)) = wv1;
}
__device__ __forceinline__ void fb_compute(const char* als, const char* bls,
    int lane, int wr, int wc, f32x4 (&acc)[4][2]) {
  const int lm = lane & 15;
  const int lk = (lane >> 4) << 4;
  const int xorv = (lm & 7) << 4;
#pragma unroll
  for (int ks = 0; ks < 2; ++ks) {
    const int kb = ks * 64 + lk;
    bf16x8 ah[4], bq[2];
#pragma unroll
    for (int i = 0; i < 4; ++i)
      ah[i] = *(const bf16x8*)(als + (((wr * 64 + i * 16 + lm) * 128 + kb) ^ xorv));
#pragma unroll
    for (int j = 0; j < 2; ++j)
      bq[j] = *(const bf16x8*)(bls + (((wc * 32 + j * 16 + lm) * 128 + kb) ^ xorv));
#pragma unroll
    for (int i = 0; i < 4; ++i)
#pragma unroll
      for (int j = 0; j < 2; ++j)
        acc[i][j] = __builtin_amdgcn_mfma_f32_16x16x32_bf16(ah[i], bq[j], acc[i][j], 0, 0, 0);
  }
}
__global__ __launch_bounds__(512, 2) void dqt_gemm_fb(
    const float* __restrict__ X, const int* __restrict__ T,
    const float* __restrict__ S, float* __restrict__ C) {
  int b = blockIdx.x;
  int wg = (b & 7) * 256 + (b >> 3);
  int bm = wg >> 5, bn = wg & 31;
  const int row0 = bm * 128, col0 = bn * 128;
  const int tid = threadIdx.x, lane = tid & 63, wid = tid >> 6;
  const int wr = wid >> 2, wc = wid & 3;
  __shared__ __align__(16) short lds_a[128 * 64];
  __shared__ __align__(16) short lds_b[128 * 64];
  char* als = (char*)lds_a;
  char* bls = (char*)lds_b;
  const int srow = tid >> 2, kq = tid & 3;
  const int arow_g = row0 + srow, brow_g = col0 + srow;
  f32x4 acc[4][2] = {};
  StageRegs rA, rB;
  fb_issue(rA, X, T, S, arow_g, brow_g, 0, kq);
#pragma unroll 1
  for (int p = 0; p < 32; ++p) {
    fb_stage(rA, als, bls, srow, kq);
    __syncthreads();
    fb_issue(rB, X, T, S, arow_g, brow_g, 2 * p + 1, kq);
    fb_compute(als, bls, lane, wr, wc, acc);
    __syncthreads();
    fb_stage(rB, als, bls, srow, kq);
    __syncthreads();
    if (p + 1 < 32) fb_issue(rA, X, T, S, arow_g, brow_g, 2 * p + 2, kq);
    fb_compute(als, bls, lane, wr, wc, acc);
    __syncthreads();
  }
  const int crow0 = row0 + wr * 64 + ((lane >> 4) << 2);
#pragma unroll
  for (int i = 0; i < 4; ++i)
#pragma unroll
    for (int j = 0; j < 2; ++j) {
      int colc = col0 + wc * 32 + j * 16 + (lane & 15);
#pragma unroll
      for (int q = 0; q < 4; ++q)
        C[(size_t)(crow0 + i * 16 + q) * N_DIM + colc] = acc[i][j][q];
    }
}

extern "C" void kernel_launch(void* const* d_in, const int* in_sizes, int n_in,
                              void* d_out, int out_size, void* d_ws, size_t ws_size,
                              hipStream_t stream) {
  const float* X = (const float*)d_in[0];
  const int* T = (const int*)d_in[1];
  const float* S = (const float*)d_in[2];
  float* C = (float*)d_out;
  if (ws_size >= A_BYTES + B_BYTES) {
    char* Aws = (char*)d_ws;
    char* Bws = (char*)d_ws + A_BYTES;
    prep_ab<<<2048, 256, 0, stream>>>(X, T, S, Aws, Bws);
    dqt_gemm32<<<512, 512, 0, stream>>>(Aws, Bws, C);
  } else {
    dqt_gemm_fb<<<2048, 512, 0, stream>>>(X, T, S, C);
  }
}

// Round 6
// 512.471 us; speedup vs baseline: 1.1058x; 1.1058x over previous
//
#include <hip/hip_runtime.h>
#include <hip/hip_bf16.h>

// DQTLinear: C[M][N] = x[M][K] @ W^T, W[n][k] = ternary[n][k]*scales[n*32+k/128]
// M=8192, N=4096, K=4096. ternary arrives as int32 (harness upcasts int inputs).
// R6: prep_v2 = LDS-transpose prepass (coalesced both sides; ws layout unchanged
// from R5 which passed). GEMM: 2-phase merged schedule (4 barriers/tile), same
// proven staging slots + vmcnt(4) ledger + 32x32x16 MFMA maps validated in R5.

#define M_DIM 8192
#define N_DIM 4096
#define K_DIM 4096
#define NGRP 32

#define BM 256
#define BN 256
#define NT 64               // K tiles of 64
#define TILE_B 32768        // per matrix per K-tile (2 kk-halves x 16 KiB)
#define A_BYTES (32ull * NT * TILE_B)   // 64 MiB
#define B_BYTES (16ull * NT * TILE_B)   // 32 MiB

typedef float f32x4 __attribute__((ext_vector_type(4)));
typedef float f32x16 __attribute__((ext_vector_type(16)));
typedef short bf16x8 __attribute__((ext_vector_type(8)));

// RNE fp32->bf16 (valid for non-NaN inputs), packs two into one u32.
__device__ __forceinline__ unsigned bfpack(unsigned lo, unsigned hi) {
  lo = (lo + 0x7FFFu + ((lo >> 16) & 1u)) >> 16;
  hi = (hi + 0x7FFFu + ((hi >> 16) & 1u)) & 0xFFFF0000u;
  return lo | hi;
}

// ---------------- prep_v2: LDS-transpose prepass ----------------
// ws chunk layout (16B chunk c): slot = c>>10 ; s = (c>>8)&3 ; r = c&255
// A: slot = (a*64+kt)*2+kk ; data = bf16(X[a*256+r][kt*64+kk*32+s*8+e])
// B: slot = (bn*64+kt)*2+kk ; data = bf16(T*scale), same k mapping.
// One workgroup per (slab, kt): reads 256 rows x 64 k coalesced (lanes sweep k),
// transposes through a 32 KiB LDS tile (XOR k8<<4 bank swizzle), writes ws linear.
__global__ __launch_bounds__(256) void prep_v2(
    const float* __restrict__ X, const int* __restrict__ T,
    const float* __restrict__ S, char* __restrict__ A, char* __restrict__ B) {
  __shared__ __align__(16) char tile[32768];
  const int t = threadIdx.x;  // 256
  const int wg = blockIdx.x;  // 0..3071  (A: 0..2047, B: 2048..3071)

  if (wg < 2048) {
    const int a = wg >> 6, kt = wg & 63;
    const float* src = X + ((size_t)a * 256) * K_DIM + kt * 64;
#pragma unroll
    for (int j = 0; j < 8; ++j) {
      const int r = j * 32 + (t >> 3);
      const int k8 = t & 7;                  // kk = k8>>2, s = k8&3
      const uint4* p = reinterpret_cast<const uint4*>(src + (size_t)r * K_DIM + k8 * 8);
      uint4 u = p[0], v = p[1];
      uint4 o;
      o.x = bfpack(u.x, u.y);
      o.y = bfpack(u.z, u.w);
      o.z = bfpack(v.x, v.y);
      o.w = bfpack(v.z, v.w);
      const int byte = ((k8 >> 2) << 14) + ((k8 & 3) << 12) + (r << 4);
      *reinterpret_cast<uint4*>(tile + (byte ^ (k8 << 4))) = o;
    }
    __syncthreads();
    char* dst = A + ((size_t)(a * 64 + kt) << 15);
#pragma unroll
    for (int j = 0; j < 8; ++j) {
      const int lc = j * 256 + t;
      uint4 d = *reinterpret_cast<const uint4*>(
          tile + ((lc << 4) ^ (((lc >> 8) & 7) << 4)));
      *reinterpret_cast<uint4*>(dst + (size_t)lc * 16) = d;
    }
  } else {
    const int wgb = wg - 2048;
    const int bn = wgb >> 6, kt = wgb & 63;
    const int* src = T + ((size_t)bn * 256) * K_DIM + kt * 64;
    const int grp = kt >> 1;
#pragma unroll
    for (int j = 0; j < 8; ++j) {
      const int r = j * 32 + (t >> 3);
      const int k8 = t & 7;
      const int gn = bn * 256 + r;
      unsigned su = __builtin_bit_cast(unsigned, S[(size_t)gn * NGRP + grp]);
      unsigned sb = (su + 0x7FFFu + ((su >> 16) & 1u)) >> 16;  // bf16(scale), >0
      const int4* p = reinterpret_cast<const int4*>(src + (size_t)r * K_DIM + k8 * 8);
      int4 u = p[0], v = p[1];
      int tv[8] = {u.x, u.y, u.z, u.w, v.x, v.y, v.z, v.w};
      unsigned h[8];
#pragma unroll
      for (int e = 0; e < 8; ++e) {
        unsigned sgn = ((unsigned)(tv[e] >> 31)) & 0x8000u;
        h[e] = tv[e] ? (sb | sgn) : 0u;
      }
      uint4 o;
      o.x = h[0] | (h[1] << 16);
      o.y = h[2] | (h[3] << 16);
      o.z = h[4] | (h[5] << 16);
      o.w = h[6] | (h[7] << 16);
      const int byte = ((k8 >> 2) << 14) + ((k8 & 3) << 12) + (r << 4);
      *reinterpret_cast<uint4*>(tile + (byte ^ (k8 << 4))) = o;
    }
    __syncthreads();
    char* dst = B + ((size_t)(bn * 64 + kt) << 15);
#pragma unroll
    for (int j = 0; j < 8; ++j) {
      const int lc = j * 256 + t;
      uint4 d = *reinterpret_cast<const uint4*>(
          tile + ((lc << 4) ^ (((lc >> 8) & 7) << 4)));
      *reinterpret_cast<uint4*>(dst + (size_t)lc * 16) = d;
    }
  }
}

// ---------------- main GEMM: 256x256, 8 waves, 32x32x16, 2-phase ----------------
__device__ __forceinline__ void gload16(const char* g, const char* l) {
  __builtin_amdgcn_global_load_lds(
      (const __attribute__((address_space(1))) void*)g,
      (__attribute__((address_space(3))) void*)l, 16, 0, 0);
}

__global__ __launch_bounds__(512, 2) void dqt_gemm32(
    const char* __restrict__ Aws, const char* __restrict__ Bws,
    float* __restrict__ C) {
  __shared__ __align__(16) char lds[131072];  // 2 bufs x {A_lo,A_hi,B_lo,B_hi} x 16KiB

  // T1: chunked XCD swizzle; per XCD 4 bm x 16 bn, bn fast
  int b = blockIdx.x;             // 512
  int xcd = b & 7, idx = b >> 3;
  int bm = xcd * 4 + (idx >> 4);  // 0..31
  int bn = idx & 15;              // 0..15

  const int tid = threadIdx.x;
  const int lane = tid & 63;
  const int wid = tid >> 6;       // 8 waves
  const int wr = wid >> 2;        // M half (128 rows)
  const int wc = wid & 3;         // N quarter (64 cols)
  const int l31 = lane & 31;
  const int lh = lane >> 5;

  const char* pA = Aws + ((size_t)bm << 21) + wid * 2048 + lane * 16;
  const char* pB = Bws + ((size_t)bn << 21) + wid * 2048 + lane * 16;
  const int sbase = wid * 2048;

#define STAGE(dstoff, src)                                \
  do {                                                    \
    gload16((src), lds + (dstoff) + sbase);               \
    gload16((src) + 1024, lds + (dstoff) + sbase + 1024); \
  } while (0)

  // frag byte offsets within a 16 KiB kk-slot: slice(k)*4096 + row*16
  const int aoff = lh * 4096 + (wr * 128 + l31) * 16;          // + m*512, +8192 for k0=16
  const int boff = 32768 + lh * 4096 + (wc * 64 + l31) * 16;   // + n*512

  f32x16 acc[4][2] = {};

  // Prologue: tile0 full (8 loads) + tile1 kk0 pair (4 loads); retire tile0.
  STAGE(0, pA);                      // buf0 A kk0 (t0)
  STAGE(16384, pA + 16384);          // buf0 A kk1
  STAGE(32768, pB);                  // buf0 B kk0
  STAGE(49152, pB + 16384);          // buf0 B kk1
  STAGE(65536, pA + 32768);          // buf1 A kk0 (t1)
  STAGE(65536 + 32768, pB + 32768);  // buf1 B kk0
  asm volatile("s_waitcnt vmcnt(4)" ::: "memory");
  __builtin_amdgcn_s_barrier();

#pragma unroll 1
  for (int t = 0; t < NT; ++t) {
    const int cb = (t & 1) << 16;
    const int nb = (~t & 1) << 16;
    const char* sA1 = pA + (t + 1) * TILE_B;
    const char* sB1 = pB + (t + 1) * TILE_B;
    const char* sA2 = pA + (t + 2) * TILE_B;
    const char* sB2 = pB + (t + 2) * TILE_B;
    bf16x8 af0[4], af1[4], bq0[2], bq1[2];

    // ---- ph1: kk0 (k0=0 and k0=16) ; stage next-tile kk1 pair into nb ----
#pragma unroll
    for (int m = 0; m < 4; ++m) {
      af0[m] = *(const bf16x8*)(lds + cb + aoff + m * 512);
      af1[m] = *(const bf16x8*)(lds + cb + 8192 + aoff + m * 512);
    }
#pragma unroll
    for (int n = 0; n < 2; ++n) {
      bq0[n] = *(const bf16x8*)(lds + cb + boff + n * 512);
      bq1[n] = *(const bf16x8*)(lds + cb + 8192 + boff + n * 512);
    }
    if (t + 1 < NT) {
      STAGE(nb + 16384, sA1 + 16384);
      STAGE(nb + 49152, sB1 + 16384);
    }
    __builtin_amdgcn_s_barrier();
    __builtin_amdgcn_s_setprio(1);
#pragma unroll
    for (int m = 0; m < 4; ++m)
#pragma unroll
      for (int n = 0; n < 2; ++n)
        acc[m][n] = __builtin_amdgcn_mfma_f32_32x32x16_bf16(af0[m], bq0[n], acc[m][n], 0, 0, 0);
#pragma unroll
    for (int m = 0; m < 4; ++m)
#pragma unroll
      for (int n = 0; n < 2; ++n)
        acc[m][n] = __builtin_amdgcn_mfma_f32_32x32x16_bf16(af1[m], bq1[n], acc[m][n], 0, 0, 0);
    __builtin_amdgcn_s_setprio(0);
    __builtin_amdgcn_s_barrier();

    // ---- ph2: kk1 ; stage t+2 kk0 pair into cb ; counted vmcnt ----
#pragma unroll
    for (int m = 0; m < 4; ++m) {
      af0[m] = *(const bf16x8*)(lds + cb + 16384 + aoff + m * 512);
      af1[m] = *(const bf16x8*)(lds + cb + 16384 + 8192 + aoff + m * 512);
    }
#pragma unroll
    for (int n = 0; n < 2; ++n) {
      bq0[n] = *(const bf16x8*)(lds + cb + 16384 + boff + n * 512);
      bq1[n] = *(const bf16x8*)(lds + cb + 16384 + 8192 + boff + n * 512);
    }
    if (t + 2 < NT) {
      STAGE(cb + 0, sA2);        // cb kk0 consumed in ph1; all waves past barrier
      STAGE(cb + 32768, sB2);
    }
    __builtin_amdgcn_s_barrier();
    __builtin_amdgcn_s_setprio(1);
#pragma unroll
    for (int m = 0; m < 4; ++m)
#pragma unroll
      for (int n = 0; n < 2; ++n)
        acc[m][n] = __builtin_amdgcn_mfma_f32_32x32x16_bf16(af0[m], bq0[n], acc[m][n], 0, 0, 0);
#pragma unroll
    for (int m = 0; m < 4; ++m)
#pragma unroll
      for (int n = 0; n < 2; ++n)
        acc[m][n] = __builtin_amdgcn_mfma_f32_32x32x16_bf16(af1[m], bq1[n], acc[m][n], 0, 0, 0);
    __builtin_amdgcn_s_setprio(0);
    // retires t+1's remaining 4 (kk1) + leaves t+2's kk0 4 in flight
    if (t < NT - 3)
      asm volatile("s_waitcnt vmcnt(4)" ::: "memory");
    else
      asm volatile("s_waitcnt vmcnt(0)" ::: "memory");
    __builtin_amdgcn_s_barrier();
  }

  // Epilogue: 32x32 C/D map: col = lane&31, row = (q&3) + 8*(q>>2) + 4*(lane>>5)
  const int row0 = bm * BM + wr * 128 + 4 * lh;
  const int col0 = bn * BN + wc * 64 + l31;
#pragma unroll
  for (int m = 0; m < 4; ++m)
#pragma unroll
    for (int n = 0; n < 2; ++n) {
      float* cp = C + (size_t)(row0 + m * 32) * N_DIM + col0 + n * 32;
#pragma unroll
      for (int q = 0; q < 16; ++q)
        cp[(size_t)((q & 3) + 8 * (q >> 2)) * N_DIM] = acc[m][n][q];
    }
#undef STAGE
}

// ---------------- fallback (proven R2 kernel) if ws too small ----------------
struct StageRegs { float4 a0, a1, a2, a3; int4 b0, b1, b2, b3; float s; };

__device__ __forceinline__ void fb_issue(StageRegs& r, const float* __restrict__ X,
    const int* __restrict__ T, const float* __restrict__ S,
    int arow_g, int brow_g, int kt, int kq) {
  const int kbase = kt * 64;
  const float4* pa = reinterpret_cast<const float4*>(X + (size_t)arow_g * K_DIM + kbase + kq * 16);
  r.a0 = pa[0]; r.a1 = pa[1]; r.a2 = pa[2]; r.a3 = pa[3];
  const int4* pb = reinterpret_cast<const int4*>(T + (size_t)brow_g * K_DIM + kbase + kq * 16);
  r.b0 = pb[0]; r.b1 = pb[1]; r.b2 = pb[2]; r.b3 = pb[3];
  r.s = S[(size_t)brow_g * NGRP + (kt >> 1)];
}
__device__ __forceinline__ void fb_stage(const StageRegs& r, char* als, char* bls,
                                         int rrow, int kq) {
  const int xorv = (rrow & 7) << 4;
  const int base = rrow * 128 + kq * 32;
  const float* xf = (const float*)&r.a0;
  const int* wi = (const int*)&r.b0;
  bf16x8 av0, av1, wv0, wv1;
#pragma unroll
  for (int e = 0; e < 8; ++e) {
    av0[e] = __builtin_bit_cast(short, __float2bfloat16(xf[e]));
    av1[e] = __builtin_bit_cast(short, __float2bfloat16(xf[8 + e]));
    wv0[e] = __builtin_bit_cast(short, __float2bfloat16((float)wi[e] * r.s));
    wv1[e] = __builtin_bit_cast(short, __float2bfloat16((float)wi[8 + e] * r.s));
  }
  *(bf16x8*)(als + ((base) ^ xorv)) = av0;
  *(bf16x8*)(als + ((base + 16) ^ xorv)) = av1;
  *(bf16x8*)(bls + ((base) ^ xorv)) = wv0;
  *(bf16x8*)(bls + ((base + 16) ^ xorv)) = wv1;
}
__device__ __forceinline__ void fb_compute(const char* als, const char* bls,
    int lane, int wr, int wc, f32x4 (&acc)[4][2]) {
  const int lm = lane & 15;
  const int lk = (lane >> 4) << 4;
  const int xorv = (lm & 7) << 4;
#pragma unroll
  for (int ks = 0; ks < 2; ++ks) {
    const int kb = ks * 64 + lk;
    bf16x8 ah[4], bq[2];
#pragma unroll
    for (int i = 0; i < 4; ++i)
      ah[i] = *(const bf16x8*)(als + (((wr * 64 + i * 16 + lm) * 128 + kb) ^ xorv));
#pragma unroll
    for (int j = 0; j < 2; ++j)
      bq[j] = *(const bf16x8*)(bls + (((wc * 32 + j * 16 + lm) * 128 + kb) ^ xorv));
#pragma unroll
    for (int i = 0; i < 4; ++i)
#pragma unroll
      for (int j = 0; j < 2; ++j)
        acc[i][j] = __builtin_amdgcn_mfma_f32_16x16x32_bf16(ah[i], bq[j], acc[i][j], 0, 0, 0);
  }
}
__global__ __launch_bounds__(512, 2) void dqt_gemm_fb(
    const float* __restrict__ X, const int* __restrict__ T,
    const float* __restrict__ S, float* __restrict__ C) {
  int b = blockIdx.x;
  int wg = (b & 7) * 256 + (b >> 3);
  int bm = wg >> 5, bn = wg & 31;
  const int row0 = bm * 128, col0 = bn * 128;
  const int tid = threadIdx.x, lane = tid & 63, wid = tid >> 6;
  const int wr = wid >> 2, wc = wid & 3;
  __shared__ __align__(16) short lds_a[128 * 64];
  __shared__ __align__(16) short lds_b[128 * 64];
  char* als = (char*)lds_a;
  char* bls = (char*)lds_b;
  const int srow = tid >> 2, kq = tid & 3;
  const int arow_g = row0 + srow, brow_g = col0 + srow;
  f32x4 acc[4][2] = {};
  StageRegs rA, rB;
  fb_issue(rA, X, T, S, arow_g, brow_g, 0, kq);
#pragma unroll 1
  for (int p = 0; p < 32; ++p) {
    fb_stage(rA, als, bls, srow, kq);
    __syncthreads();
    fb_issue(rB, X, T, S, arow_g, brow_g, 2 * p + 1, kq);
    fb_compute(als, bls, lane, wr, wc, acc);
    __syncthreads();
    fb_stage(rB, als, bls, srow, kq);
    __syncthreads();
    if (p + 1 < 32) fb_issue(rA, X, T, S, arow_g, brow_g, 2 * p + 2, kq);
    fb_compute(als, bls, lane, wr, wc, acc);
    __syncthreads();
  }
  const int crow0 = row0 + wr * 64 + ((lane >> 4) << 2);
#pragma unroll
  for (int i = 0; i < 4; ++i)
#pragma unroll
    for (int j = 0; j < 2; ++j) {
      int colc = col0 + wc * 32 + j * 16 + (lane & 15);
#pragma unroll
      for (int q = 0; q < 4; ++q)
        C[(size_t)(crow0 + i * 16 + q) * N_DIM + colc] = acc[i][j][q];
    }
}

extern "C" void kernel_launch(void* const* d_in, const int* in_sizes, int n_in,
                              void* d_out, int out_size, void* d_ws, size_t ws_size,
                              hipStream_t stream) {
  const float* X = (const float*)d_in[0];
  const int* T = (const int*)d_in[1];
  const float* S = (const float*)d_in[2];
  float* C = (float*)d_out;
  if (ws_size >= A_BYTES + B_BYTES) {
    char* Aws = (char*)d_ws;
    char* Bws = (char*)d_ws + A_BYTES;
    prep_v2<<<3072, 256, 0, stream>>>(X, T, S, Aws, Bws);
    dqt_gemm32<<<512, 512, 0, stream>>>(Aws, Bws, C);
  } else {
    dqt_gemm_fb<<<2048, 512, 0, stream>>>(X, T, S, C);
  }
}